// Round 2
// baseline (112.333 us; speedup 1.0000x reference)
//
#include <hip/hip_runtime.h>
#include <hip/hip_bf16.h>

#define LOG2E 1.44269504088896340736f

__device__ __forceinline__ float fast_exp2(float x) {
#if __has_builtin(__builtin_amdgcn_exp2f)
    return __builtin_amdgcn_exp2f(x);
#else
    return exp2f(x);
#endif
}

// ---------------------------------------------------------------------------
// Stage 1: fused QKV projection with transposed outputs (unchanged from R1).
// grid = 512 blocks x 256 threads.
//   bid <  256 : Q path — rows rb*8..rb*8+7 of x   -> qT[b][h][q]
//   bid >= 256 : KV path — rows rb*8..rb*8+7 of emb -> kT[b][h][j], vT[b][h][j]
// ---------------------------------------------------------------------------
__global__ __launch_bounds__(256) void proj_kernel(
    const float* __restrict__ x, const float* __restrict__ emb,
    const float* __restrict__ Wq, const float* __restrict__ Wk,
    const float* __restrict__ Wv,
    float* __restrict__ qT, float* __restrict__ kT, float* __restrict__ vT)
{
    __shared__ __align__(16) float sx[4096];    // 8 rows x 512
    __shared__ __align__(16) float sred[4096];  // partial-sum reduction buffer
    const int t   = threadIdx.x;
    const int bid = blockIdx.x;
    const bool isQ = (bid < 256);
    const int rb  = isQ ? bid : (bid - 256);

    const float* src = (isQ ? x : emb) + (size_t)rb * 8 * 512;
    #pragma unroll
    for (int i = 0; i < 16; ++i) sx[i * 256 + t] = src[i * 256 + t];
    __syncthreads();

    const int b  = rb >> 7;
    const int q0 = (rb << 3) & 1023;

    if (isQ) {
        const int cp = (t & 31) * 2;
        const int g  = t >> 5;
        const int d0 = g * 64;
        float acc0[8], acc1[8];
        #pragma unroll
        for (int r = 0; r < 8; ++r) { acc0[r] = 0.f; acc1[r] = 0.f; }
        for (int dd = 0; dd < 64; dd += 4) {
            const int d = d0 + dd;
            float2 w0 = *(const float2*)&Wq[(d + 0) * 64 + cp];
            float2 w1 = *(const float2*)&Wq[(d + 1) * 64 + cp];
            float2 w2 = *(const float2*)&Wq[(d + 2) * 64 + cp];
            float2 w3 = *(const float2*)&Wq[(d + 3) * 64 + cp];
            #pragma unroll
            for (int r = 0; r < 8; ++r) {
                float4 xv = *(const float4*)&sx[r * 512 + d];
                acc0[r] = fmaf(xv.x, w0.x, acc0[r]); acc1[r] = fmaf(xv.x, w0.y, acc1[r]);
                acc0[r] = fmaf(xv.y, w1.x, acc0[r]); acc1[r] = fmaf(xv.y, w1.y, acc1[r]);
                acc0[r] = fmaf(xv.z, w2.x, acc0[r]); acc1[r] = fmaf(xv.z, w2.y, acc1[r]);
                acc0[r] = fmaf(xv.w, w3.x, acc0[r]); acc1[r] = fmaf(xv.w, w3.y, acc1[r]);
            }
        }
        #pragma unroll
        for (int r = 0; r < 8; ++r)
            *(float2*)&sred[g * 512 + r * 64 + cp] = make_float2(acc0[r], acc1[r]);
        __syncthreads();
        #pragma unroll
        for (int p = 0; p < 2; ++p) {
            int idx = p * 256 + t;
            int r = idx >> 6, h = idx & 63;
            float s = 0.f;
            #pragma unroll
            for (int g2 = 0; g2 < 8; ++g2) s += sred[g2 * 512 + r * 64 + h];
            qT[(size_t)(b * 64 + h) * 1024 + q0 + r] = s;
        }
    } else {
        const int cp = (t & 63) * 2;
        const int g  = t >> 6;
        const int d0 = g * 128;
        const float* Wsel = (cp < 64) ? (Wk + cp) : (Wv + (cp - 64));
        float acc0[8], acc1[8];
        #pragma unroll
        for (int r = 0; r < 8; ++r) { acc0[r] = 0.f; acc1[r] = 0.f; }
        for (int dd = 0; dd < 128; dd += 4) {
            const int d = d0 + dd;
            float2 w0 = *(const float2*)&Wsel[(d + 0) * 64];
            float2 w1 = *(const float2*)&Wsel[(d + 1) * 64];
            float2 w2 = *(const float2*)&Wsel[(d + 2) * 64];
            float2 w3 = *(const float2*)&Wsel[(d + 3) * 64];
            #pragma unroll
            for (int r = 0; r < 8; ++r) {
                float4 xv = *(const float4*)&sx[r * 512 + d];
                acc0[r] = fmaf(xv.x, w0.x, acc0[r]); acc1[r] = fmaf(xv.x, w0.y, acc1[r]);
                acc0[r] = fmaf(xv.y, w1.x, acc0[r]); acc1[r] = fmaf(xv.y, w1.y, acc1[r]);
                acc0[r] = fmaf(xv.z, w2.x, acc0[r]); acc1[r] = fmaf(xv.z, w2.y, acc1[r]);
                acc0[r] = fmaf(xv.w, w3.x, acc0[r]); acc1[r] = fmaf(xv.w, w3.y, acc1[r]);
            }
        }
        #pragma unroll
        for (int r = 0; r < 8; ++r)
            *(float2*)&sred[g * 1024 + r * 128 + cp] = make_float2(acc0[r], acc1[r]);
        __syncthreads();
        #pragma unroll
        for (int p = 0; p < 4; ++p) {
            int idx = p * 256 + t;
            int r = idx >> 7, c = idx & 127;
            float s = 0.f;
            #pragma unroll
            for (int g2 = 0; g2 < 4; ++g2) s += sred[g2 * 1024 + r * 128 + c];
            if (c < 64) kT[(size_t)(b * 64 + c) * 1024 + q0 + r] = s;
            else        vT[(size_t)(b * 64 + (c - 64)) * 1024 + q0 + r] = s;
        }
    }
}

// ---------------------------------------------------------------------------
// Stage 2: attention partials. head_dim==1 => o[q] = sum_j e^(q_s*k_j) v_j / sum_j e^(..).
// No stabilization needed: |s| <= ~30, e^30 ~ 1e13 << fp32 max; sums stay in range.
// grid = B*64*4 = 512 blocks: block (b,h,js) handles j-chunk js*256..+255 for ALL 1024 q.
// Each thread owns 4 q's (q = t + 256*i), so one k4/v4 LDS read feeds 16 exp+fma ops
// (4x fewer LDS instrs/CU than 1 q/thread — LDS pipe drops below the exp floor).
// Writes per-chunk partial num/den; merged in stage 3.
// ---------------------------------------------------------------------------
__global__ __launch_bounds__(256) void attn_kernel(
    const float* __restrict__ qT, const float* __restrict__ kT,
    const float* __restrict__ vT,
    float* __restrict__ numP, float* __restrict__ denP)
{
    __shared__ __align__(16) float kc[256];
    __shared__ __align__(16) float vc[256];
    const int t   = threadIdx.x;
    const int bid = blockIdx.x;           // bid = bh*4 + js
    const int js  = bid & 3;
    const int bh  = bid >> 2;             // b*64 + h
    const size_t base = (size_t)bh * 1024;
    const int j0 = js * 256;

    if (t < 64)       ((float4*)kc)[t]      = ((const float4*)(kT + base + j0))[t];
    else if (t < 128) ((float4*)vc)[t - 64] = ((const float4*)(vT + base + j0))[t - 64];
    __syncthreads();

    const float a0 = qT[base +       t] * LOG2E;
    const float a1 = qT[base + 256 + t] * LOG2E;
    const float a2 = qT[base + 512 + t] * LOG2E;
    const float a3 = qT[base + 768 + t] * LOG2E;

    float d0 = 0.f, d1 = 0.f, d2 = 0.f, d3 = 0.f;
    float n0 = 0.f, n1 = 0.f, n2 = 0.f, n3 = 0.f;
    const float4* kc4 = (const float4*)kc;
    const float4* vc4 = (const float4*)vc;

#define ATT_STEP(ai, di, ni, kk, vv) \
    { float e_ = fast_exp2((ai) * (kk)); (di) += e_; (ni) = fmaf(e_, (vv), (ni)); }

    #pragma unroll 4
    for (int j = 0; j < 64; ++j) {
        float4 k4 = kc4[j];
        float4 v4 = vc4[j];
        ATT_STEP(a0, d0, n0, k4.x, v4.x); ATT_STEP(a1, d1, n1, k4.x, v4.x);
        ATT_STEP(a2, d2, n2, k4.x, v4.x); ATT_STEP(a3, d3, n3, k4.x, v4.x);
        ATT_STEP(a0, d0, n0, k4.y, v4.y); ATT_STEP(a1, d1, n1, k4.y, v4.y);
        ATT_STEP(a2, d2, n2, k4.y, v4.y); ATT_STEP(a3, d3, n3, k4.y, v4.y);
        ATT_STEP(a0, d0, n0, k4.z, v4.z); ATT_STEP(a1, d1, n1, k4.z, v4.z);
        ATT_STEP(a2, d2, n2, k4.z, v4.z); ATT_STEP(a3, d3, n3, k4.z, v4.z);
        ATT_STEP(a0, d0, n0, k4.w, v4.w); ATT_STEP(a1, d1, n1, k4.w, v4.w);
        ATT_STEP(a2, d2, n2, k4.w, v4.w); ATT_STEP(a3, d3, n3, k4.w, v4.w);
    }
#undef ATT_STEP

    // partial layout: [bh*4 + js][1024] = [bid][1024]; coalesced stores
    const size_t pb = (size_t)bid * 1024;
    numP[pb +       t] = n0;  denP[pb +       t] = d0;
    numP[pb + 256 + t] = n1;  denP[pb + 256 + t] = d1;
    numP[pb + 512 + t] = n2;  denP[pb + 512 + t] = d2;
    numP[pb + 768 + t] = n3;  denP[pb + 768 + t] = d3;
}

// ---------------------------------------------------------------------------
// Stage 3: merge partials (sum 4 chunks, divide) + out = O @ Wo + bo.
// grid = 256 blocks (8 (b,q)-rows each), 256 threads (2 output cols each).
// ---------------------------------------------------------------------------
__global__ __launch_bounds__(256) void oproj_kernel(
    const float* __restrict__ numP, const float* __restrict__ denP,
    const float* __restrict__ Wo, const float* __restrict__ bo,
    float* __restrict__ out)
{
    __shared__ __align__(16) float so[512];   // 8 rows x 64 h
    const int t  = threadIdx.x;
    const int rb = blockIdx.x;
    const size_t r0 = (size_t)rb * 8;         // global row = b*1024 + q
    const int b  = rb >> 7;
    const int q0 = (int)(r0 & 1023);

    #pragma unroll
    for (int p = 0; p < 2; ++p) {
        int idx = p * 256 + t;
        int r = idx >> 6, h = idx & 63;
        size_t pb = ((size_t)(b * 64 + h) * 4) * 1024 + (size_t)(q0 + r);
        float ns = (numP[pb] + numP[pb + 1024]) + (numP[pb + 2048] + numP[pb + 3072]);
        float ds = (denP[pb] + denP[pb + 1024]) + (denP[pb + 2048] + denP[pb + 3072]);
        so[r * 64 + h] = ns / ds;
    }
    __syncthreads();

    const int d2 = t * 2;
    float2 bv = *(const float2*)&bo[d2];
    float acc0[8], acc1[8];
    #pragma unroll
    for (int r = 0; r < 8; ++r) { acc0[r] = bv.x; acc1[r] = bv.y; }
    for (int hh = 0; hh < 64; hh += 4) {
        float2 w0 = *(const float2*)&Wo[(hh + 0) * 512 + d2];
        float2 w1 = *(const float2*)&Wo[(hh + 1) * 512 + d2];
        float2 w2 = *(const float2*)&Wo[(hh + 2) * 512 + d2];
        float2 w3 = *(const float2*)&Wo[(hh + 3) * 512 + d2];
        #pragma unroll
        for (int r = 0; r < 8; ++r) {
            float4 s4 = *(const float4*)&so[r * 64 + hh];
            acc0[r] = fmaf(s4.x, w0.x, acc0[r]); acc1[r] = fmaf(s4.x, w0.y, acc1[r]);
            acc0[r] = fmaf(s4.y, w1.x, acc0[r]); acc1[r] = fmaf(s4.y, w1.y, acc1[r]);
            acc0[r] = fmaf(s4.z, w2.x, acc0[r]); acc1[r] = fmaf(s4.z, w2.y, acc1[r]);
            acc0[r] = fmaf(s4.w, w3.x, acc0[r]); acc1[r] = fmaf(s4.w, w3.y, acc1[r]);
        }
    }
    #pragma unroll
    for (int r = 0; r < 8; ++r)
        *(float2*)&out[(r0 + r) * 512 + d2] = make_float2(acc0[r], acc1[r]);
}

extern "C" void kernel_launch(void* const* d_in, const int* in_sizes, int n_in,
                              void* d_out, int out_size, void* d_ws, size_t ws_size,
                              hipStream_t stream)
{
    const float* x   = (const float*)d_in[0];
    const float* emb = (const float*)d_in[1];
    const float* Wq  = (const float*)d_in[2];
    const float* Wk  = (const float*)d_in[3];
    const float* Wv  = (const float*)d_in[4];
    const float* Wo  = (const float*)d_in[5];
    const float* bo  = (const float*)d_in[6];
    float* out = (float*)d_out;

    // workspace: qT/kT/vT [B*64,1024] + numP/denP [B*64*4,1024] — 5.8 MB total
    float* qT   = (float*)d_ws;
    float* kT   = qT + 131072;
    float* vT   = kT + 131072;
    float* numP = vT + 131072;
    float* denP = numP + 524288;

    proj_kernel <<<512, 256, 0, stream>>>(x, emb, Wq, Wk, Wv, qT, kT, vT);
    attn_kernel <<<512, 256, 0, stream>>>(qT, kT, vT, numP, denP);
    oproj_kernel<<<256, 256, 0, stream>>>(numP, denP, Wo, bo, out);
}

// Round 3
// 110.747 us; speedup vs baseline: 1.0143x; 1.0143x over previous
//
#include <hip/hip_runtime.h>
#include <hip/hip_bf16.h>

#define LOG2E 1.44269504088896340736f

typedef float v2f __attribute__((ext_vector_type(2)));

// Guaranteed single-instruction exp2: builtin if present, raw v_exp_f32 otherwise.
// (s_nop covers the CDNA trans->use wait state the compiler can't see through asm.)
__device__ __forceinline__ float fast_exp2(float x) {
#if __has_builtin(__builtin_amdgcn_exp2f)
    return __builtin_amdgcn_exp2f(x);
#else
    float r;
    asm volatile("v_exp_f32 %0, %1\n\ts_nop 0" : "=v"(r) : "v"(x));
    return r;
#endif
}

// ---------------------------------------------------------------------------
// Stage 1: fused QKV projection with transposed outputs (unchanged control).
// ---------------------------------------------------------------------------
__global__ __launch_bounds__(256) void proj_kernel(
    const float* __restrict__ x, const float* __restrict__ emb,
    const float* __restrict__ Wq, const float* __restrict__ Wk,
    const float* __restrict__ Wv,
    float* __restrict__ qT, float* __restrict__ kT, float* __restrict__ vT)
{
    __shared__ __align__(16) float sx[4096];
    __shared__ __align__(16) float sred[4096];
    const int t   = threadIdx.x;
    const int bid = blockIdx.x;
    const bool isQ = (bid < 256);
    const int rb  = isQ ? bid : (bid - 256);

    const float* src = (isQ ? x : emb) + (size_t)rb * 8 * 512;
    #pragma unroll
    for (int i = 0; i < 16; ++i) sx[i * 256 + t] = src[i * 256 + t];
    __syncthreads();

    const int b  = rb >> 7;
    const int q0 = (rb << 3) & 1023;

    if (isQ) {
        const int cp = (t & 31) * 2;
        const int g  = t >> 5;
        const int d0 = g * 64;
        float acc0[8], acc1[8];
        #pragma unroll
        for (int r = 0; r < 8; ++r) { acc0[r] = 0.f; acc1[r] = 0.f; }
        for (int dd = 0; dd < 64; dd += 4) {
            const int d = d0 + dd;
            float2 w0 = *(const float2*)&Wq[(d + 0) * 64 + cp];
            float2 w1 = *(const float2*)&Wq[(d + 1) * 64 + cp];
            float2 w2 = *(const float2*)&Wq[(d + 2) * 64 + cp];
            float2 w3 = *(const float2*)&Wq[(d + 3) * 64 + cp];
            #pragma unroll
            for (int r = 0; r < 8; ++r) {
                float4 xv = *(const float4*)&sx[r * 512 + d];
                acc0[r] = fmaf(xv.x, w0.x, acc0[r]); acc1[r] = fmaf(xv.x, w0.y, acc1[r]);
                acc0[r] = fmaf(xv.y, w1.x, acc0[r]); acc1[r] = fmaf(xv.y, w1.y, acc1[r]);
                acc0[r] = fmaf(xv.z, w2.x, acc0[r]); acc1[r] = fmaf(xv.z, w2.y, acc1[r]);
                acc0[r] = fmaf(xv.w, w3.x, acc0[r]); acc1[r] = fmaf(xv.w, w3.y, acc1[r]);
            }
        }
        #pragma unroll
        for (int r = 0; r < 8; ++r)
            *(float2*)&sred[g * 512 + r * 64 + cp] = make_float2(acc0[r], acc1[r]);
        __syncthreads();
        #pragma unroll
        for (int p = 0; p < 2; ++p) {
            int idx = p * 256 + t;
            int r = idx >> 6, h = idx & 63;
            float s = 0.f;
            #pragma unroll
            for (int g2 = 0; g2 < 8; ++g2) s += sred[g2 * 512 + r * 64 + h];
            qT[(size_t)(b * 64 + h) * 1024 + q0 + r] = s;
        }
    } else {
        const int cp = (t & 63) * 2;
        const int g  = t >> 6;
        const int d0 = g * 128;
        const float* Wsel = (cp < 64) ? (Wk + cp) : (Wv + (cp - 64));
        float acc0[8], acc1[8];
        #pragma unroll
        for (int r = 0; r < 8; ++r) { acc0[r] = 0.f; acc1[r] = 0.f; }
        for (int dd = 0; dd < 128; dd += 4) {
            const int d = d0 + dd;
            float2 w0 = *(const float2*)&Wsel[(d + 0) * 64];
            float2 w1 = *(const float2*)&Wsel[(d + 1) * 64];
            float2 w2 = *(const float2*)&Wsel[(d + 2) * 64];
            float2 w3 = *(const float2*)&Wsel[(d + 3) * 64];
            #pragma unroll
            for (int r = 0; r < 8; ++r) {
                float4 xv = *(const float4*)&sx[r * 512 + d];
                acc0[r] = fmaf(xv.x, w0.x, acc0[r]); acc1[r] = fmaf(xv.x, w0.y, acc1[r]);
                acc0[r] = fmaf(xv.y, w1.x, acc0[r]); acc1[r] = fmaf(xv.y, w1.y, acc1[r]);
                acc0[r] = fmaf(xv.z, w2.x, acc0[r]); acc1[r] = fmaf(xv.z, w2.y, acc1[r]);
                acc0[r] = fmaf(xv.w, w3.x, acc0[r]); acc1[r] = fmaf(xv.w, w3.y, acc1[r]);
            }
        }
        #pragma unroll
        for (int r = 0; r < 8; ++r)
            *(float2*)&sred[g * 1024 + r * 128 + cp] = make_float2(acc0[r], acc1[r]);
        __syncthreads();
        #pragma unroll
        for (int p = 0; p < 4; ++p) {
            int idx = p * 256 + t;
            int r = idx >> 7, c = idx & 127;
            float s = 0.f;
            #pragma unroll
            for (int g2 = 0; g2 < 4; ++g2) s += sred[g2 * 1024 + r * 128 + c];
            if (c < 64) kT[(size_t)(b * 64 + c) * 1024 + q0 + r] = s;
            else        vT[(size_t)(b * 64 + (c - 64)) * 1024 + q0 + r] = s;
        }
    }
}

// ---------------------------------------------------------------------------
// Stage 2: attention partials, packed-fp32 inner loop.
// Per 4 elems (4 q x 1 k): 2 v_pk_mul + 4 v_exp + 2 v_pk_add + 2 v_pk_fma
// -> 3 VALU cyc/elem < 4 trans cyc/elem: transcendental-pipe-bound (~3.4 us).
// ---------------------------------------------------------------------------
__global__ __launch_bounds__(256) void attn_kernel(
    const float* __restrict__ qT, const float* __restrict__ kT,
    const float* __restrict__ vT,
    float* __restrict__ numP, float* __restrict__ denP)
{
    __shared__ __align__(16) float kc[256];
    __shared__ __align__(16) float vc[256];
    const int t   = threadIdx.x;
    const int bid = blockIdx.x;           // bid = bh*4 + js
    const int js  = bid & 3;
    const int bh  = bid >> 2;
    const size_t base = (size_t)bh * 1024;
    const int j0 = js * 256;

    if (t < 64)       ((float4*)kc)[t]      = ((const float4*)(kT + base + j0))[t];
    else if (t < 128) ((float4*)vc)[t - 64] = ((const float4*)(vT + base + j0))[t - 64];
    __syncthreads();

    v2f a01, a23;
    a01.x = qT[base +       t] * LOG2E;
    a01.y = qT[base + 256 + t] * LOG2E;
    a23.x = qT[base + 512 + t] * LOG2E;
    a23.y = qT[base + 768 + t] * LOG2E;

    v2f d01 = {0.f, 0.f}, d23 = {0.f, 0.f};
    v2f n01 = {0.f, 0.f}, n23 = {0.f, 0.f};
    const float4* kc4 = (const float4*)kc;
    const float4* vc4 = (const float4*)vc;

#define ATT_STEP(kk, vv)                                   \
    {                                                      \
        v2f t01 = a01 * (kk);                              \
        v2f t23 = a23 * (kk);                              \
        v2f e01, e23;                                      \
        e01.x = fast_exp2(t01.x); e01.y = fast_exp2(t01.y);\
        e23.x = fast_exp2(t23.x); e23.y = fast_exp2(t23.y);\
        d01 += e01; d23 += e23;                            \
        n01 += e01 * (vv); n23 += e23 * (vv);              \
    }

    #pragma unroll 4
    for (int j = 0; j < 64; ++j) {
        float4 k4 = kc4[j];
        float4 v4 = vc4[j];
        ATT_STEP(k4.x, v4.x);
        ATT_STEP(k4.y, v4.y);
        ATT_STEP(k4.z, v4.z);
        ATT_STEP(k4.w, v4.w);
    }
#undef ATT_STEP

    const size_t pb = (size_t)bid * 1024;
    numP[pb +       t] = n01.x;  denP[pb +       t] = d01.x;
    numP[pb + 256 + t] = n01.y;  denP[pb + 256 + t] = d01.y;
    numP[pb + 512 + t] = n23.x;  denP[pb + 512 + t] = d23.x;
    numP[pb + 768 + t] = n23.y;  denP[pb + 768 + t] = d23.y;
}

// ---------------------------------------------------------------------------
// Stage 3: merge partials + out = O @ Wo + bo (unchanged control).
// ---------------------------------------------------------------------------
__global__ __launch_bounds__(256) void oproj_kernel(
    const float* __restrict__ numP, const float* __restrict__ denP,
    const float* __restrict__ Wo, const float* __restrict__ bo,
    float* __restrict__ out)
{
    __shared__ __align__(16) float so[512];
    const int t  = threadIdx.x;
    const int rb = blockIdx.x;
    const size_t r0 = (size_t)rb * 8;
    const int b  = rb >> 7;
    const int q0 = (int)(r0 & 1023);

    #pragma unroll
    for (int p = 0; p < 2; ++p) {
        int idx = p * 256 + t;
        int r = idx >> 6, h = idx & 63;
        size_t pb = ((size_t)(b * 64 + h) * 4) * 1024 + (size_t)(q0 + r);
        float ns = (numP[pb] + numP[pb + 1024]) + (numP[pb + 2048] + numP[pb + 3072]);
        float ds = (denP[pb] + denP[pb + 1024]) + (denP[pb + 2048] + denP[pb + 3072]);
        so[r * 64 + h] = ns / ds;
    }
    __syncthreads();

    const int d2 = t * 2;
    float2 bv = *(const float2*)&bo[d2];
    float acc0[8], acc1[8];
    #pragma unroll
    for (int r = 0; r < 8; ++r) { acc0[r] = bv.x; acc1[r] = bv.y; }
    for (int hh = 0; hh < 64; hh += 4) {
        float2 w0 = *(const float2*)&Wo[(hh + 0) * 512 + d2];
        float2 w1 = *(const float2*)&Wo[(hh + 1) * 512 + d2];
        float2 w2 = *(const float2*)&Wo[(hh + 2) * 512 + d2];
        float2 w3 = *(const float2*)&Wo[(hh + 3) * 512 + d2];
        #pragma unroll
        for (int r = 0; r < 8; ++r) {
            float4 s4 = *(const float4*)&so[r * 64 + hh];
            acc0[r] = fmaf(s4.x, w0.x, acc0[r]); acc1[r] = fmaf(s4.x, w0.y, acc1[r]);
            acc0[r] = fmaf(s4.y, w1.x, acc0[r]); acc1[r] = fmaf(s4.y, w1.y, acc1[r]);
            acc0[r] = fmaf(s4.z, w2.x, acc0[r]); acc1[r] = fmaf(s4.z, w2.y, acc1[r]);
            acc0[r] = fmaf(s4.w, w3.x, acc0[r]); acc1[r] = fmaf(s4.w, w3.y, acc1[r]);
        }
    }
    #pragma unroll
    for (int r = 0; r < 8; ++r)
        *(float2*)&out[(r0 + r) * 512 + d2] = make_float2(acc0[r], acc1[r]);
}

extern "C" void kernel_launch(void* const* d_in, const int* in_sizes, int n_in,
                              void* d_out, int out_size, void* d_ws, size_t ws_size,
                              hipStream_t stream)
{
    const float* x   = (const float*)d_in[0];
    const float* emb = (const float*)d_in[1];
    const float* Wq  = (const float*)d_in[2];
    const float* Wk  = (const float*)d_in[3];
    const float* Wv  = (const float*)d_in[4];
    const float* Wo  = (const float*)d_in[5];
    const float* bo  = (const float*)d_in[6];
    float* out = (float*)d_out;

    float* qT   = (float*)d_ws;
    float* kT   = qT + 131072;
    float* vT   = kT + 131072;
    float* numP = vT + 131072;
    float* denP = numP + 524288;

    proj_kernel <<<512, 256, 0, stream>>>(x, emb, Wq, Wk, Wv, qT, kT, vT);
    attn_kernel <<<512, 256, 0, stream>>>(qT, kT, vT, numP, denP);
    oproj_kernel<<<256, 256, 0, stream>>>(numP, denP, Wo, bo, out);
}